// Round 6
// baseline (864.995 us; speedup 1.0000x reference)
//
#include <hip/hip_runtime.h>
#include <hip/hip_fp16.h>
#include <math.h>

#define NN 100000
#define EE 1600000
#define DD 128
#define NBUCK 196          // ceil(NN / 512) buckets of 512 dst nodes
#define NBLKP 196          // partition blocks, 8192 edges each
#define EPB 8192           // edges per partition block

// ---------- bucketed CSR build ----------
__global__ __launch_bounds__(256) void part_hist_k(const int* __restrict__ dst, int* __restrict__ bcnt) {
    __shared__ int lc[NBUCK];
    int t = threadIdx.x, blk = blockIdx.x;
    if (t < NBUCK) lc[t] = 0;
    __syncthreads();
    int e0 = blk * EPB;
    for (int i = t; i < EPB; i += 256) {
        int e = e0 + i;
        if (e < EE) atomicAdd(&lc[dst[e] >> 9], 1);
    }
    __syncthreads();
    if (t < NBUCK) bcnt[t * NBLKP + blk] = lc[t];
}

__global__ __launch_bounds__(256) void scanBB_k(const int* __restrict__ bcnt, int* __restrict__ ebase,
                                                int* __restrict__ btot) {
    __shared__ int sh[256];
    int t = threadIdx.x, b = blockIdx.x;
    int c = (t < NBLKP) ? bcnt[b * NBLKP + t] : 0;
    sh[t] = c;
    __syncthreads();
    for (int off = 1; off < 256; off <<= 1) {
        int v = (t >= off) ? sh[t - off] : 0;
        __syncthreads();
        sh[t] += v;
        __syncthreads();
    }
    if (t < NBLKP) ebase[b * NBLKP + t] = sh[t] - c;
    if (t == 255) btot[b] = sh[255];
}

__global__ __launch_bounds__(256) void scanBT_k(const int* __restrict__ btot, int* __restrict__ bstart,
                                                int* __restrict__ offsets) {
    __shared__ int sh[256];
    int t = threadIdx.x;
    int c = (t < NBUCK) ? btot[t] : 0;
    sh[t] = c;
    __syncthreads();
    for (int off = 1; off < 256; off <<= 1) {
        int v = (t >= off) ? sh[t - off] : 0;
        __syncthreads();
        sh[t] += v;
        __syncthreads();
    }
    if (t < NBUCK) bstart[t] = sh[t] - c;
    if (t == 0) { bstart[NBUCK] = EE; offsets[NN] = EE; }
}

__global__ __launch_bounds__(256) void part_k(const int* __restrict__ src, const int* __restrict__ dst,
                                              const int* __restrict__ bstart, const int* __restrict__ ebase,
                                              int2* __restrict__ ebuf) {
    __shared__ int cur[NBUCK];
    int t = threadIdx.x, blk = blockIdx.x;
    if (t < NBUCK) cur[t] = bstart[t] + ebase[t * NBLKP + blk];
    __syncthreads();
    int e0 = blk * EPB;
    for (int i = t; i < EPB; i += 256) {
        int e = e0 + i;
        if (e < EE) {
            int s = src[e], d = dst[e];
            int p = atomicAdd(&cur[d >> 9], 1);
            ebuf[p] = make_int2(s, d);
        }
    }
}

__global__ __launch_bounds__(512) void bucket_sort_k(const int2* __restrict__ ebuf,
                                                     const int* __restrict__ bstart,
                                                     int* __restrict__ offsets,
                                                     int* __restrict__ ssrc) {
    __shared__ int sh[512];
    __shared__ int cur[512];
    int t = threadIdx.x, b = blockIdx.x;
    int d0 = b << 9;
    int beg = bstart[b], end = bstart[b + 1];

    cur[t] = 0;
    __syncthreads();
    for (int e = beg + t; e < end; e += 512) atomicAdd(&cur[ebuf[e].y - d0], 1);
    __syncthreads();
    int c = cur[t];
    sh[t] = c;
    __syncthreads();
    for (int off = 1; off < 512; off <<= 1) {
        int v = (t >= off) ? sh[t - off] : 0;
        __syncthreads();
        sh[t] += v;
        __syncthreads();
    }
    int excl = sh[t] - c;
    if (d0 + t < NN) offsets[d0 + t] = beg + excl;
    cur[t] = beg + excl;
    __syncthreads();
    for (int e = beg + t; e < end; e += 512) {
        int2 ed = ebuf[e];
        int p = atomicAdd(&cur[ed.y - d0], 1);
        ssrc[p] = ed.x;
    }
}

// ---------------- GEMM (unchanged from R4) ----------------
template <int MODE>
__global__ __launch_bounds__(256, 3) void gemm_k(const float* __restrict__ X,
                                                 const float* __restrict__ W,
                                                 const float* __restrict__ bias,
                                                 const float* __restrict__ av_src,
                                                 const float* __restrict__ av_dst,
                                                 float* __restrict__ Yf,
                                                 __half* __restrict__ Yh,
                                                 float* __restrict__ alpha_src,
                                                 float* __restrict__ alpha_dst) {
    __shared__ float sX[32 * 128];
    __shared__ float sW[32 * 128];
    int t = threadIdx.x;
    int row0 = blockIdx.x * 128;
    int tm = t >> 4, tn = t & 15;

    float acc[2][2][4][4] = {};

    const float4* W4 = (const float4*)W;
    float4* sW4 = (float4*)sW;
    float4* sX4 = (float4*)sX;

    int xm = t >> 1;
    int xrow = row0 + xm;
    bool xvalid = xrow < NN;
    const float4* Xrow4 = (const float4*)(X + (size_t)xrow * DD);
    int xko = (t & 1) * 16;

    for (int kc = 0; kc < DD; kc += 32) {
        __syncthreads();
#pragma unroll
        for (int q = 0; q < 4; q++) {
            int ko = xko + q * 4;
            float4 xv = xvalid ? Xrow4[(kc + ko) >> 2] : make_float4(0.f, 0.f, 0.f, 0.f);
            sX[(ko + 0) * 128 + xm] = xv.x;
            sX[(ko + 1) * 128 + xm] = xv.y;
            sX[(ko + 2) * 128 + xm] = xv.z;
            sX[(ko + 3) * 128 + xm] = xv.w;
        }
#pragma unroll
        for (int q = 0; q < 4; q++) {
            int idx = q * 256 + t;
            sW4[idx] = W4[kc * 32 + idx];
        }
        __syncthreads();
#pragma unroll 8
        for (int k = 0; k < 32; k++) {
            float4 x0 = sX4[k * 32 + tm];
            float4 x1 = sX4[k * 32 + 16 + tm];
            float4 w0 = sW4[k * 32 + tn];
            float4 w1 = sW4[k * 32 + 16 + tn];
            float xa[2][4] = {{x0.x, x0.y, x0.z, x0.w}, {x1.x, x1.y, x1.z, x1.w}};
            float wb[2][4] = {{w0.x, w0.y, w0.z, w0.w}, {w1.x, w1.y, w1.z, w1.w}};
#pragma unroll
            for (int a = 0; a < 2; a++)
#pragma unroll
                for (int b = 0; b < 2; b++)
#pragma unroll
                    for (int i = 0; i < 4; i++)
#pragma unroll
                        for (int j = 0; j < 4; j++)
                            acc[a][b][i][j] += xa[a][i] * wb[b][j];
        }
    }

    if (MODE == 0) {
        float4 ba = *(const float4*)(bias + tn * 4);
        float4 bb = *(const float4*)(bias + 64 + tn * 4);
#pragma unroll
        for (int a = 0; a < 2; a++) {
#pragma unroll
            for (int i = 0; i < 4; i++) {
                int row = row0 + a * 64 + tm * 4 + i;
                if (row < NN) {
                    float o0[4] = {acc[a][0][i][0] + ba.x, acc[a][0][i][1] + ba.y,
                                   acc[a][0][i][2] + ba.z, acc[a][0][i][3] + ba.w};
                    float o1[4] = {acc[a][1][i][0] + bb.x, acc[a][1][i][1] + bb.y,
                                   acc[a][1][i][2] + bb.z, acc[a][1][i][3] + bb.w};
#pragma unroll
                    for (int j = 0; j < 4; j++) {
                        o0[j] = o0[j] > 0.f ? o0[j] : 0.01f * o0[j];
                        o1[j] = o1[j] > 0.f ? o1[j] : 0.01f * o1[j];
                    }
                    *(float4*)&Yf[(size_t)row * DD + tn * 4] = make_float4(o0[0], o0[1], o0[2], o0[3]);
                    *(float4*)&Yf[(size_t)row * DD + 64 + tn * 4] = make_float4(o1[0], o1[1], o1[2], o1[3]);
                }
            }
        }
    } else {
        float4 asa = *(const float4*)(av_src + tn * 4);
        float4 asb = *(const float4*)(av_src + 64 + tn * 4);
        float4 ada = *(const float4*)(av_dst + tn * 4);
        float4 adb = *(const float4*)(av_dst + 64 + tn * 4);
#pragma unroll
        for (int a = 0; a < 2; a++) {
#pragma unroll
            for (int i = 0; i < 4; i++) {
                int row = row0 + a * 64 + tm * 4 + i;
                float4 o0 = make_float4(acc[a][0][i][0], acc[a][0][i][1], acc[a][0][i][2], acc[a][0][i][3]);
                float4 o1 = make_float4(acc[a][1][i][0], acc[a][1][i][1], acc[a][1][i][2], acc[a][1][i][3]);
                if (row < NN) {
                    union { __half2 h2[2]; uint2 u; } p0, p1;
                    p0.h2[0] = __floats2half2_rn(o0.x, o0.y);
                    p0.h2[1] = __floats2half2_rn(o0.z, o0.w);
                    p1.h2[0] = __floats2half2_rn(o1.x, o1.y);
                    p1.h2[1] = __floats2half2_rn(o1.z, o1.w);
                    *(uint2*)&Yh[(size_t)row * DD + tn * 4] = p0.u;
                    *(uint2*)&Yh[(size_t)row * DD + 64 + tn * 4] = p1.u;
                }
                float pa = o0.x * asa.x + o0.y * asa.y + o0.z * asa.z + o0.w * asa.w
                         + o1.x * asb.x + o1.y * asb.y + o1.z * asb.z + o1.w * asb.w;
                float pb = o0.x * ada.x + o0.y * ada.y + o0.z * ada.z + o0.w * ada.w
                         + o1.x * adb.x + o1.y * adb.y + o1.z * adb.z + o1.w * adb.w;
#pragma unroll
                for (int off = 8; off >= 1; off >>= 1) {
                    pa += __shfl_xor(pa, off);
                    pb += __shfl_xor(pb, off);
                }
                if (tn == 0 && row < NN) {
                    alpha_src[row] = pa;
                    alpha_dst[row] = pb;
                }
            }
        }
    }
}

// ---------------- Phase A: per-edge softmax weights ----------------
// one wave per dst node; writes ew[j] = {src, exp(e-m)} and invd[node] = 1/denom
__global__ __launch_bounds__(256) void edgew_k(const int* __restrict__ ssrc,
                                               const int* __restrict__ offsets,
                                               const float* __restrict__ alpha_src,
                                               const float* __restrict__ alpha_dst,
                                               int2* __restrict__ ew,
                                               float* __restrict__ invd) {
    int wid = (blockIdx.x * 256 + threadIdx.x) >> 6;
    int lane = threadIdx.x & 63;
    int beg = offsets[wid], end = offsets[wid + 1];
    float adst = alpha_dst[wid];

    float m = -INFINITY;
    for (int j = beg + lane; j < end; j += 64) {
        int s = ssrc[j];
        float e = alpha_src[s] + adst;
        e = e > 0.f ? e : 0.2f * e;
        m = fmaxf(m, e);
    }
#pragma unroll
    for (int off = 32; off >= 1; off >>= 1) m = fmaxf(m, __shfl_xor(m, off));

    float dsum = 0.f;
    for (int j = beg + lane; j < end; j += 64) {
        int s = ssrc[j];
        float e = alpha_src[s] + adst;
        e = e > 0.f ? e : 0.2f * e;
        float ex = __expf(e - m);
        dsum += ex;
        ew[j] = make_int2(s, __float_as_int(ex));
    }
#pragma unroll
    for (int off = 32; off >= 1; off >>= 1) dsum += __shfl_xor(dsum, off);
    if (lane == 0) invd[wid] = 1.0f / (dsum + 1e-16f);
}

// ---------------- Phase B: gather-accumulate + bias + LN + leaky ----------------
// one wave per dst node; per-edge (src, w) is wave-uniform -> scalar loads;
// lane c owns channels 2c, 2c+1
__global__ __launch_bounds__(256) void agg_k(const __half* __restrict__ tmp,
                                             const int2* __restrict__ ew,
                                             const int* __restrict__ offsets,
                                             const float* __restrict__ invd,
                                             const float* __restrict__ bias,
                                             const float* __restrict__ gamma,
                                             const float* __restrict__ beta,
                                             float* __restrict__ out) {
    int wid = (blockIdx.x * 256 + threadIdx.x) >> 6;
    int lane = threadIdx.x & 63;
    int beg = offsets[wid], end = offsets[wid + 1];
    const __half2* tmp2 = (const __half2*)tmp;

    float2 aA = make_float2(0.f, 0.f), aB = make_float2(0.f, 0.f);
    float2 aC = make_float2(0.f, 0.f), aD = make_float2(0.f, 0.f);

    int j = beg;
    for (; j + 7 < end; j += 8) {
        int2 e0 = ew[j + 0], e1 = ew[j + 1], e2 = ew[j + 2], e3 = ew[j + 3];
        int2 e4 = ew[j + 4], e5 = ew[j + 5], e6 = ew[j + 6], e7 = ew[j + 7];
        float2 h0 = __half22float2(tmp2[(size_t)e0.x * 64 + lane]);
        float2 h1 = __half22float2(tmp2[(size_t)e1.x * 64 + lane]);
        float2 h2 = __half22float2(tmp2[(size_t)e2.x * 64 + lane]);
        float2 h3 = __half22float2(tmp2[(size_t)e3.x * 64 + lane]);
        float2 h4 = __half22float2(tmp2[(size_t)e4.x * 64 + lane]);
        float2 h5 = __half22float2(tmp2[(size_t)e5.x * 64 + lane]);
        float2 h6 = __half22float2(tmp2[(size_t)e6.x * 64 + lane]);
        float2 h7 = __half22float2(tmp2[(size_t)e7.x * 64 + lane]);
        float w0 = __int_as_float(e0.y), w1 = __int_as_float(e1.y);
        float w2 = __int_as_float(e2.y), w3 = __int_as_float(e3.y);
        float w4 = __int_as_float(e4.y), w5 = __int_as_float(e5.y);
        float w6 = __int_as_float(e6.y), w7 = __int_as_float(e7.y);
        aA.x += w0 * h0.x; aA.y += w0 * h0.y;
        aB.x += w1 * h1.x; aB.y += w1 * h1.y;
        aC.x += w2 * h2.x; aC.y += w2 * h2.y;
        aD.x += w3 * h3.x; aD.y += w3 * h3.y;
        aA.x += w4 * h4.x; aA.y += w4 * h4.y;
        aB.x += w5 * h5.x; aB.y += w5 * h5.y;
        aC.x += w6 * h6.x; aC.y += w6 * h6.y;
        aD.x += w7 * h7.x; aD.y += w7 * h7.y;
    }
    for (; j < end; ++j) {
        int2 e0 = ew[j];
        float w0 = __int_as_float(e0.y);
        float2 h0 = __half22float2(tmp2[(size_t)e0.x * 64 + lane]);
        aA.x += w0 * h0.x; aA.y += w0 * h0.y;
    }

    float inv = invd[wid];
    float ax = (aA.x + aB.x + aC.x + aD.x) * inv + bias[2 * lane];
    float ay = (aA.y + aB.y + aC.y + aD.y) * inv + bias[2 * lane + 1];

    // layernorm over 128 channels (2 per lane)
    float s1 = ax + ay;
#pragma unroll
    for (int off = 32; off >= 1; off >>= 1) s1 += __shfl_xor(s1, off);
    float mu = s1 * (1.0f / 128.0f);
    float dx = ax - mu, dy = ay - mu;
    float s2 = dx * dx + dy * dy;
#pragma unroll
    for (int off = 32; off >= 1; off >>= 1) s2 += __shfl_xor(s2, off);
    float rstd = rsqrtf(s2 * (1.0f / 128.0f) + 1e-5f);

    float yx = dx * rstd * gamma[2 * lane] + beta[2 * lane];
    float yy = dy * rstd * gamma[2 * lane + 1] + beta[2 * lane + 1];
    yx = yx > 0.f ? yx : 0.01f * yx;
    yy = yy > 0.f ? yy : 0.01f * yy;
    ((float2*)out)[(size_t)wid * 64 + lane] = make_float2(yx, yy);
}

extern "C" void kernel_launch(void* const* d_in, const int* in_sizes, int n_in,
                              void* d_out, int out_size, void* d_ws, size_t ws_size,
                              hipStream_t stream) {
    const float* x       = (const float*)d_in[0];
    const int*   ei      = (const int*)d_in[1];
    const float* W_in    = (const float*)d_in[2];
    const float* b_in    = (const float*)d_in[3];
    const float* Wl      = (const float*)d_in[4];
    const float* att_src = (const float*)d_in[5];
    const float* att_dst = (const float*)d_in[6];
    const float* bias_l  = (const float*)d_in[7];
    const float* gamma   = (const float*)d_in[8];
    const float* beta    = (const float*)d_in[9];
    float* out = (float*)d_out;

    char* ws = (char*)d_ws;
    __half* tmp      = (__half*)ws; ws += (size_t)NN * DD * 2;   // 25.6 MB
    float* alpha_src = (float*)ws;  ws += (size_t)NN * 4;
    float* alpha_dst = (float*)ws;  ws += (size_t)NN * 4;
    float* invd      = (float*)ws;  ws += (size_t)NN * 4;
    int*   offsets   = (int*)ws;    ws += (size_t)(NN + 4) * 4;
    int*   ssrc      = (int*)ws;    ws += (size_t)EE * 4;        // 6.4 MB
    int2*  ew        = (int2*)ws;   ws += (size_t)EE * 8;        // 12.8 MB
    int2*  ebuf      = (int2*)ws;   ws += (size_t)EE * 8;        // 12.8 MB
    int*   bcnt      = (int*)ws;    ws += (size_t)NBUCK * NBLKP * 4;
    int*   ebase     = (int*)ws;    ws += (size_t)NBUCK * NBLKP * 4;
    int*   btot      = (int*)ws;    ws += (size_t)(NBUCK + 4) * 4;
    int*   bstart    = (int*)ws;    ws += (size_t)(NBUCK + 4) * 4;

    const int* esrc = ei;
    const int* edst = ei + EE;

    // bucketed CSR build (edges constant within a launch)
    part_hist_k<<<NBLKP, 256, 0, stream>>>(edst, bcnt);
    scanBB_k<<<NBUCK, 256, 0, stream>>>(bcnt, ebase, btot);
    scanBT_k<<<1, 256, 0, stream>>>(btot, bstart, offsets);
    part_k<<<NBLKP, 256, 0, stream>>>(esrc, edst, bstart, ebase, ebuf);
    bucket_sort_k<<<NBUCK, 512, 0, stream>>>(ebuf, bstart, offsets, ssrc);

    const int gemm_grid = (NN + 127) / 128;  // 782

    // input projection: h0 = leaky(x @ W_in + b_in)
    gemm_k<0><<<gemm_grid, 256, 0, stream>>>(x, W_in, b_in, nullptr, nullptr, out, nullptr, nullptr, nullptr);

    for (int i = 0; i < 4; i++) {
        gemm_k<1><<<gemm_grid, 256, 0, stream>>>(out, Wl + (size_t)i * DD * DD, nullptr,
                                                 att_src + (size_t)i * DD, att_dst + (size_t)i * DD,
                                                 nullptr, tmp, alpha_src, alpha_dst);
        edgew_k<<<NN / 4, 256, 0, stream>>>(ssrc, offsets, alpha_src, alpha_dst, ew, invd);
        agg_k<<<NN / 4, 256, 0, stream>>>(tmp, ew, offsets, invd,
                                          bias_l + (size_t)i * DD, gamma + (size_t)i * DD,
                                          beta + (size_t)i * DD, out);
    }
}